// Round 4
// baseline (76.966 us; speedup 1.0000x reference)
//
#include <hip/hip_runtime.h>
#include <stdint.h>

typedef unsigned long long u64;
typedef __attribute__((ext_vector_type(8))) short bf16x8;   // 8 bf16 (4 VGPRs)
typedef __attribute__((ext_vector_type(4))) float f32x4;    // MFMA acc

#define IN_FEATURES 256
#define UNITS 256

// sign(x) as bf16 bits: 0 for ±0, else ±1.0 (0x3F80 | signbit). Exact.
__device__ __forceinline__ ushort sgn_bf16(float f) {
    uint u = __float_as_uint(f);
    return ((u << 1) == 0u) ? (ushort)0 : (ushort)(0x3F80u | ((u >> 16) & 0x8000u));
}
__device__ __forceinline__ uint sgn_pack2(float a, float b) {
    return (uint)sgn_bf16(a) | ((uint)sgn_bf16(b) << 16);
}

// ---------------------------------------------------------------------------
// Pack kernel: wB[col][k] = sign-bf16 of w[k][col]  (transpose via LDS).
// 16 blocks x 256 threads; block b owns cols b*16..b*16+15.  (~1 us)
// ---------------------------------------------------------------------------
__global__ __launch_bounds__(256) void pack_w_bf16(const float* __restrict__ w,
                                                   ushort* __restrict__ wB) {
    __shared__ ushort ls[256][18];  // [k][c], +2 pad
    const int b = blockIdx.x;
    const int t = threadIdx.x;

    const float4* wr = (const float4*)(w + (size_t)t * UNITS + b * 16);
#pragma unroll
    for (int i = 0; i < 4; ++i) {
        const float4 v = wr[i];
        ls[t][i * 4 + 0] = sgn_bf16(v.x);
        ls[t][i * 4 + 1] = sgn_bf16(v.y);
        ls[t][i * 4 + 2] = sgn_bf16(v.z);
        ls[t][i * 4 + 3] = sgn_bf16(v.w);
    }
    __syncthreads();

    const int c = t >> 4;
    const int k0 = (t & 15) * 16;
    alignas(16) ushort tmp[16];
#pragma unroll
    for (int i = 0; i < 16; ++i) tmp[i] = ls[k0 + i][c];
    ushort* dst = wB + ((size_t)(b * 16 + c)) * IN_FEATURES + k0;
    *(uint4*)(dst) = *(const uint4*)&tmp[0];
    *(uint4*)(dst + 8) = *(const uint4*)&tmp[8];
}

// ---------------------------------------------------------------------------
// Main kernel: no LDS, no barriers, wave-private output tiles.
// Block = 256 threads (4 waves) covering 64 rows x 128 cols:
//   wave w: rows [rowbase + (w&1)*32, +32), cols [colbase + (w>>1)*64, +64)
//   -> per-wave tile 32x64 = acc[2][4] f32x4 (32 VGPRs).
// Per k-step: 4 A dwordx4 loads (global, sign-converted in regs, x tile is
// L1-resident across the block's waves), 4 B 16B loads (wB L2-resident),
// 8 MFMA. Fully unrolled -> deep MLP. Nontemporal C-stores keep out of L3
// so x stays L3-resident between replays.
// ---------------------------------------------------------------------------
__global__ __launch_bounds__(256, 4) void bdense_mfma2(const float* __restrict__ x,
                                                       const ushort* __restrict__ wB,
                                                       float* __restrict__ out) {
    const int tid = threadIdx.x;
    const int lane = tid & 63;
    const int wid = tid >> 6;
    const long rowbase = (long)(blockIdx.x >> 1) * 64 + (wid & 1) * 32;
    const int colbase = (blockIdx.x & 1) * 128 + (wid >> 1) * 64;

    const int rl = lane & 15;        // row/col within 16-tile
    const int kl = (lane >> 4) * 8;  // k-chunk base within 32-k slice

    f32x4 acc[2][4];
#pragma unroll
    for (int mt = 0; mt < 2; ++mt)
#pragma unroll
        for (int nt = 0; nt < 4; ++nt) acc[mt][nt] = (f32x4){0.f, 0.f, 0.f, 0.f};

#pragma unroll
    for (int ks = 0; ks < 8; ++ks) {
        const int kk = ks * 32 + kl;

        bf16x8 a[2], b[4];
#pragma unroll
        for (int mt = 0; mt < 2; ++mt) {
            const float4* p =
                (const float4*)(x + (rowbase + mt * 16 + rl) * IN_FEATURES + kk);
            const float4 v0 = p[0];
            const float4 v1 = p[1];
            uint4 q;
            q.x = sgn_pack2(v0.x, v0.y);
            q.y = sgn_pack2(v0.z, v0.w);
            q.z = sgn_pack2(v1.x, v1.y);
            q.w = sgn_pack2(v1.z, v1.w);
            a[mt] = *(bf16x8*)&q;
        }
#pragma unroll
        for (int nt = 0; nt < 4; ++nt) {
            b[nt] = *(const bf16x8*)&wB[(size_t)(colbase + nt * 16 + rl) * IN_FEATURES + kk];
        }
#pragma unroll
        for (int mt = 0; mt < 2; ++mt)
#pragma unroll
            for (int nt = 0; nt < 4; ++nt)
                acc[mt][nt] = __builtin_amdgcn_mfma_f32_16x16x32_bf16(
                    a[mt], b[nt], acc[mt][nt], 0, 0, 0);
    }

    // C/D map (m89-verified): col = lane&15, row = (lane>>4)*4 + reg.
    const int crow = (lane >> 4) * 4;
#pragma unroll
    for (int mt = 0; mt < 2; ++mt) {
#pragma unroll
        for (int nt = 0; nt < 4; ++nt) {
            float* op = out + (rowbase + mt * 16 + crow) * UNITS + colbase + nt * 16 + rl;
#pragma unroll
            for (int j = 0; j < 4; ++j)
                __builtin_nontemporal_store(acc[mt][nt][j], op + (size_t)j * UNITS);
        }
    }
}

// ---------------------------------------------------------------------------
// Fallback (ws too small): round-2 popcount path, known-correct.
// ---------------------------------------------------------------------------
__global__ __launch_bounds__(256) void pack_w_bits(const float* __restrict__ w,
                                                   u64* __restrict__ wp) {
    const int t = blockIdx.x;
    const int j = threadIdx.x;
    u64 s = 0, z = 0;
#pragma unroll
    for (int b = 0; b < 64; ++b) {
        const float v = w[(4 * b + t) * UNITS + j];
        s |= ((u64)(v < 0.0f)) << b;
        z |= ((u64)(v != 0.0f)) << b;
    }
    wp[j * 4 + t] = s;
    wp[1024 + j * 4 + t] = z;
}

__global__ __launch_bounds__(256) void bdense_pop(const float4* __restrict__ x4,
                                                  const u64* __restrict__ wp,
                                                  float4* __restrict__ out4) {
    const int tid = threadIdx.x;
    const int lane = tid & 63;
    const int wid = tid >> 6;
    const long row0 = (long)blockIdx.x * 32 + (long)wid * 8;

    u64 ws_[4][4], wz_[4][4];
#pragma unroll
    for (int i = 0; i < 4; ++i)
#pragma unroll
        for (int t = 0; t < 4; ++t) {
            ws_[i][t] = wp[(4 * lane + i) * 4 + t];
            wz_[i][t] = wp[1024 + (4 * lane + i) * 4 + t];
        }

#pragma unroll
    for (int r = 0; r < 8; ++r) {
        const float4 v = x4[(row0 + r) * (IN_FEATURES / 4) + lane];
        u64 rs[4], rz[4];
        rs[0] = __ballot(v.x < 0.0f); rz[0] = __ballot(v.x != 0.0f);
        rs[1] = __ballot(v.y < 0.0f); rz[1] = __ballot(v.y != 0.0f);
        rs[2] = __ballot(v.z < 0.0f); rz[2] = __ballot(v.z != 0.0f);
        rs[3] = __ballot(v.w < 0.0f); rz[3] = __ballot(v.w != 0.0f);
        float o[4];
#pragma unroll
        for (int i = 0; i < 4; ++i) {
            int nzc = 0, ngc = 0;
#pragma unroll
            for (int t = 0; t < 4; ++t) {
                const u64 nz = rz[t] & wz_[i][t];
                const u64 d = (rs[t] ^ ws_[i][t]) & nz;
                nzc += __popcll(nz);
                ngc += __popcll(d);
            }
            o[i] = (float)(nzc - 2 * ngc);
        }
        out4[(row0 + r) * (UNITS / 4) + lane] = make_float4(o[0], o[1], o[2], o[3]);
    }
}

extern "C" void kernel_launch(void* const* d_in, const int* in_sizes, int n_in,
                              void* d_out, int out_size, void* d_ws, size_t ws_size,
                              hipStream_t stream) {
    const float* x = (const float*)d_in[0];
    const float* w = (const float*)d_in[1];
    float* out = (float*)d_out;

    const int batch = in_sizes[0] / IN_FEATURES;  // 65536

    if (ws_size >= (size_t)UNITS * IN_FEATURES * sizeof(ushort)) {  // 128 KB
        ushort* wB = (ushort*)d_ws;
        pack_w_bf16<<<16, 256, 0, stream>>>(w, wB);
        // 64 rows x 128 cols per block -> (batch/64) * 2 blocks
        bdense_mfma2<<<(batch / 64) * 2, 256, 0, stream>>>(x, wB, out);
    } else {
        u64* wp = (u64*)d_ws;  // 16 KB
        pack_w_bits<<<4, 256, 0, stream>>>(w, wp);
        bdense_pop<<<batch / 32, 256, 0, stream>>>((const float4*)x, wp, (float4*)out);
    }
}

// Round 5
// 32.733 us; speedup vs baseline: 2.3513x; 2.3513x over previous
//
#include <hip/hip_runtime.h>
#include <stdint.h>

typedef unsigned long long u64;
typedef __attribute__((ext_vector_type(8))) short bf16x8;   // 8 bf16 (4 VGPRs)
typedef __attribute__((ext_vector_type(4))) float f32x4;    // MFMA acc

#define IN_FEATURES 256
#define UNITS 256
#define BM 64          // rows per block (main kernel)
#define LDK 264        // padded LDS stride in ushorts (528 B)

// sign(x) as bf16 bits: 0 for ±0, else ±1.0 (0x3F80 | signbit). Exact.
__device__ __forceinline__ ushort sgn_bf16(float f) {
    uint u = __float_as_uint(f);
    return ((u << 1) == 0u) ? (ushort)0 : (ushort)(0x3F80u | ((u >> 16) & 0x8000u));
}
__device__ __forceinline__ uint sgn_pack2(float a, float b) {
    return (uint)sgn_bf16(a) | ((uint)sgn_bf16(b) << 16);
}

// ---------------------------------------------------------------------------
// Pack kernel: w -> sign-bf16 in MFMA *fragment layout*, so the main kernel's
// B loads are perfectly coalesced (zero address divergence).
// Fragment f=(ks,ct,lane): col = ct*16 + (lane&15), k = ks*32 + (lane>>4)*8 .. +8
// fragB element index: ((ks*16 + ct)*64 + lane) * 8 ushorts.  Total 128 KB.
// Grid 16 blocks (one per ct), 256 threads.
// ---------------------------------------------------------------------------
__global__ __launch_bounds__(256) void pack_w_frag(const float* __restrict__ w,
                                                   ushort* __restrict__ fragB) {
    __shared__ ushort ls[256][17];  // [k][c], +1 pad
    const int ct = blockIdx.x;      // col-tile 0..15
    const int t = threadIdx.x;

    // Phase 1: thread t reads w row k=t, cols ct*16..+15 (4x float4)
    const float4* wr = (const float4*)(w + (size_t)t * UNITS + ct * 16);
#pragma unroll
    for (int i = 0; i < 4; ++i) {
        const float4 v = wr[i];
        ls[t][i * 4 + 0] = sgn_bf16(v.x);
        ls[t][i * 4 + 1] = sgn_bf16(v.y);
        ls[t][i * 4 + 2] = sgn_bf16(v.z);
        ls[t][i * 4 + 3] = sgn_bf16(v.w);
    }
    __syncthreads();

    // Phase 2: each thread emits 2 fragments (8 ks x 64 lanes = 512 per ct)
#pragma unroll
    for (int h = 0; h < 2; ++h) {
        const int f = t + h * 256;
        const int ks = f >> 6;        // 0..7
        const int lane = f & 63;
        const int c = lane & 15;
        const int k0 = ks * 32 + (lane >> 4) * 8;
        alignas(16) ushort tmp[8];
#pragma unroll
        for (int j = 0; j < 8; ++j) tmp[j] = ls[k0 + j][c];
        *(uint4*)(fragB + ((size_t)(ks * 16 + ct) * 64 + lane) * 8) = *(const uint4*)tmp;
    }
}

// ---------------------------------------------------------------------------
// Main kernel: LDS-staged A (coalesced), fragment-layout B (coalesced, L2),
// 16x16x32 bf16 MFMA. Block = 4 waves, 64 rows x 256 cols; wave w owns cols
// [w*64, w*64+64) as 4x4 16x16 tiles.
// ---------------------------------------------------------------------------
__global__ __launch_bounds__(256, 4) void bdense_mfma3(const float4* __restrict__ x4,
                                                       const ushort* __restrict__ fragB,
                                                       float* __restrict__ out) {
    __shared__ ushort xs[BM][LDK];  // 33792 B

    const int tid = threadIdx.x;
    const int lane = tid & 63;
    const int wid = tid >> 6;
    const long row0 = (long)blockIdx.x * BM;

    // --- stage: 64 rows x 256 k, fully coalesced float4 loads ---
#pragma unroll
    for (int i = 0; i < 16; ++i) {
        const int f = i * 256 + tid;
        const int r = f >> 6;         // row 0..63
        const int kq = f & 63;        // float4 index within row
        const float4 v = x4[(row0 + r) * (IN_FEATURES / 4) + kq];
        const uint u0 = sgn_pack2(v.x, v.y);
        const uint u1 = sgn_pack2(v.z, v.w);
        *(uint2*)&xs[r][kq * 4] = make_uint2(u0, u1);
    }
    __syncthreads();

    f32x4 acc[4][4];
#pragma unroll
    for (int mt = 0; mt < 4; ++mt)
#pragma unroll
        for (int nt = 0; nt < 4; ++nt) acc[mt][nt] = (f32x4){0.f, 0.f, 0.f, 0.f};

    const int rl = lane & 15;
    const int klb = (lane >> 4) * 8;
    const int ct0 = wid * 4;  // this wave's first col-tile

#pragma unroll
    for (int ks = 0; ks < 8; ++ks) {
        const int kk = ks * 32 + klb;

        bf16x8 a[4], b[4];
#pragma unroll
        for (int mt = 0; mt < 4; ++mt)
            a[mt] = *(const bf16x8*)&xs[mt * 16 + rl][kk];        // ds_read_b128

        const ushort* bp = fragB + ((size_t)(ks * 16 + ct0) * 64 + lane) * 8;
#pragma unroll
        for (int nt = 0; nt < 4; ++nt)
            b[nt] = *(const bf16x8*)(bp + nt * 512);              // coalesced 1KB/wave

#pragma unroll
        for (int mt = 0; mt < 4; ++mt)
#pragma unroll
            for (int nt = 0; nt < 4; ++nt)
                acc[mt][nt] = __builtin_amdgcn_mfma_f32_16x16x32_bf16(
                    a[mt], b[nt], acc[mt][nt], 0, 0, 0);
    }

    // --- store: C/D map col=lane&15, row=(lane>>4)*4+reg (m89-verified) ---
    const int crow = (lane >> 4) * 4;
    const int colbase = wid * 64;
#pragma unroll
    for (int mt = 0; mt < 4; ++mt) {
#pragma unroll
        for (int nt = 0; nt < 4; ++nt) {
            float* op = out + (row0 + mt * 16 + crow) * UNITS + colbase + nt * 16 + rl;
#pragma unroll
            for (int j = 0; j < 4; ++j) op[(size_t)j * UNITS] = acc[mt][nt][j];
        }
    }
}

// ---------------------------------------------------------------------------
// Fallback (ws too small): round-2 popcount path, known-correct.
// ---------------------------------------------------------------------------
__global__ __launch_bounds__(256) void pack_w_bits(const float* __restrict__ w,
                                                   u64* __restrict__ wp) {
    const int t = blockIdx.x;
    const int j = threadIdx.x;
    u64 s = 0, z = 0;
#pragma unroll
    for (int b = 0; b < 64; ++b) {
        const float v = w[(4 * b + t) * UNITS + j];
        s |= ((u64)(v < 0.0f)) << b;
        z |= ((u64)(v != 0.0f)) << b;
    }
    wp[j * 4 + t] = s;
    wp[1024 + j * 4 + t] = z;
}

__global__ __launch_bounds__(256) void bdense_pop(const float4* __restrict__ x4,
                                                  const u64* __restrict__ wp,
                                                  float4* __restrict__ out4) {
    const int tid = threadIdx.x;
    const int lane = tid & 63;
    const int wid = tid >> 6;
    const long row0 = (long)blockIdx.x * 32 + (long)wid * 8;

    u64 ws_[4][4], wz_[4][4];
#pragma unroll
    for (int i = 0; i < 4; ++i)
#pragma unroll
        for (int t = 0; t < 4; ++t) {
            ws_[i][t] = wp[(4 * lane + i) * 4 + t];
            wz_[i][t] = wp[1024 + (4 * lane + i) * 4 + t];
        }

#pragma unroll
    for (int r = 0; r < 8; ++r) {
        const float4 v = x4[(row0 + r) * (IN_FEATURES / 4) + lane];
        u64 rs[4], rz[4];
        rs[0] = __ballot(v.x < 0.0f); rz[0] = __ballot(v.x != 0.0f);
        rs[1] = __ballot(v.y < 0.0f); rz[1] = __ballot(v.y != 0.0f);
        rs[2] = __ballot(v.z < 0.0f); rz[2] = __ballot(v.z != 0.0f);
        rs[3] = __ballot(v.w < 0.0f); rz[3] = __ballot(v.w != 0.0f);
        float o[4];
#pragma unroll
        for (int i = 0; i < 4; ++i) {
            int nzc = 0, ngc = 0;
#pragma unroll
            for (int t = 0; t < 4; ++t) {
                const u64 nz = rz[t] & wz_[i][t];
                const u64 d = (rs[t] ^ ws_[i][t]) & nz;
                nzc += __popcll(nz);
                ngc += __popcll(d);
            }
            o[i] = (float)(nzc - 2 * ngc);
        }
        out4[(row0 + r) * (UNITS / 4) + lane] = make_float4(o[0], o[1], o[2], o[3]);
    }
}

extern "C" void kernel_launch(void* const* d_in, const int* in_sizes, int n_in,
                              void* d_out, int out_size, void* d_ws, size_t ws_size,
                              hipStream_t stream) {
    const float* x = (const float*)d_in[0];
    const float* w = (const float*)d_in[1];
    float* out = (float*)d_out;

    const int batch = in_sizes[0] / IN_FEATURES;  // 65536

    if (ws_size >= (size_t)UNITS * IN_FEATURES * sizeof(ushort)) {  // 128 KB
        ushort* fragB = (ushort*)d_ws;
        pack_w_frag<<<16, 256, 0, stream>>>(w, fragB);
        bdense_mfma3<<<batch / BM, 256, 0, stream>>>((const float4*)x, fragB, out);
    } else {
        u64* wp = (u64*)d_ws;  // 16 KB
        pack_w_bits<<<4, 256, 0, stream>>>(w, wp);
        bdense_pop<<<batch / 32, 256, 0, stream>>>((const float4*)x, wp, (float4*)out);
    }
}